// Round 18
// baseline (245.233 us; speedup 1.0000x reference)
//
#include <hip/hip_runtime.h>
#include <hip/hip_bf16.h>

using bf16 = __hip_bfloat16;
typedef __bf16 bf16x8 __attribute__((ext_vector_type(8)));
typedef float f32x4 __attribute__((ext_vector_type(4)));
typedef short short8 __attribute__((ext_vector_type(8)));
typedef _Float16 h2 __attribute__((ext_vector_type(2)));

#define AS1(p) ((const __attribute__((address_space(1))) void*)(p))
#define AS3(p) ((__attribute__((address_space(3))) void*)(p))

#define YSTRIDE 4368  // 66*66 padded to 273*16B

// ---------------------------------------------------------------------------
// Weights: Wt[tap = p*3+q][oc][ic] bf16
// ---------------------------------------------------------------------------
__global__ void prep_wt_k(const float* __restrict__ w, bf16* __restrict__ wt) {
  const int o = blockIdx.x, i = threadIdx.x;
  const float* wp = w + (size_t)(o * 256 + i) * 9;
#pragma unroll
  for (int p = 0; p < 9; ++p)
    wt[(size_t)p * 65536 + o * 256 + i] = __float2bfloat16(wp[p]);
}

// ---------------------------------------------------------------------------
// Zero ONLY the xpad border ring (rows 0/65, cols 0/65) -- runs every call.
// Row 65 doubles as the all-zero redirect target for tap-union staging.
// ---------------------------------------------------------------------------
__global__ void zring_k(bf16* __restrict__ xpad) {
  const int bid = blockIdx.x;
  const int n = bid / 33, cg = bid - n * 33;
  const int t = threadIdx.x;
  const int cell = cg * 8 + (t >> 5);
  if (cell >= 260) return;
  int row, col;
  if (cell < 66) { row = 0; col = cell; }
  else if (cell < 132) { row = 65; col = cell - 66; }
  else if (cell < 196) { row = cell - 131; col = 0; }
  else { row = cell - 195; col = 65; }
  const int ch = (t & 31) * 8;
  short8 z = {0, 0, 0, 0, 0, 0, 0, 0};
  *(short8*)(xpad + (((size_t)n * 66 + row) * 66 + col) * 256 + ch) = z;
}

// ---------------------------------------------------------------------------
// x NCHW fp32 -> padded NHWC bf16 [n][66][66][256] (interior only).
// Coalesced reads: lane = (c = t>>2, ixq = t&3), 64B contiguous per lane.
// ---------------------------------------------------------------------------
__global__ void xpose_k(const float* __restrict__ x, bf16* __restrict__ xpad) {
  const int b = blockIdx.x;
  const int icb = b & 3, iy = (b >> 2) & 63, n = b >> 8;
  __shared__ bf16 lds[64][72];
  const int t = threadIdx.x;
  const int c = t >> 2, ixq = t & 3;
  const float* src = x + (((size_t)(n * 256 + icb * 64 + c) * 64 + iy) * 64);
#pragma unroll
  for (int rep = 0; rep < 4; ++rep) {
    const int ix0 = ixq * 16 + rep * 4;
    float4 v = *reinterpret_cast<const float4*>(src + ix0);
    lds[ix0 + 0][c] = __float2bfloat16(v.x);
    lds[ix0 + 1][c] = __float2bfloat16(v.y);
    lds[ix0 + 2][c] = __float2bfloat16(v.z);
    lds[ix0 + 3][c] = __float2bfloat16(v.w);
  }
  __syncthreads();
  const int ix = t >> 2, cseg = (t & 3) * 16;
  bf16* dst = xpad + (((size_t)(n * 66 + iy + 1) * 66 + ix + 1) * 256 + icb * 64 + cseg);
  *reinterpret_cast<short8*>(dst) = *reinterpret_cast<const short8*>(&lds[ix][cseg]);
  *reinterpret_cast<short8*>(dst + 8) = *reinterpret_cast<const short8*>(&lds[ix][cseg + 8]);
}

// ---------------------------------------------------------------------------
// Bijective XCD swizzle (m204)
// ---------------------------------------------------------------------------
__device__ __forceinline__ int xcdswz(int b, int n) {
  const int q = n >> 3, r = n & 7;
  const int xcd = b & 7, idx = b >> 3;
  return (xcd < r ? xcd * (q + 1) : r * (q + 1) + (xcd - r) * q) + idx;
}

// ---------------------------------------------------------------------------
// Pass A v6: 128oc x 256m per block, 512 thr (8 waves = 2 oc x 4 m,
// acc[4][4] => ~64 VGPR + 64 AGPR = 128 unified regs -> 16 waves/CU =
// 2 BLOCKS/CU). Single-buffered W (16 KB) + tap-union X (42 KB) = 58 KB
// LDS -> both blocks fit; the co-resident block hides each stage-drain
// (m114 cross-block overlap -- the mechanism R11/R14's in-block pipelining
// could not buy at 1 block/CU). Loop: stage -> sync -> compute -> sync.
// Tap-union X staging (R16-proven): X staged once per 64-ch slice as a
// 256+MAXS-row union; taps read at row offsets S[tap]; b-wrap cells
// coincide with xpad's zero ring; rows past M redirect to zero row 65.
// y stored PLANAR fp16: y[plane][n][c][YSTRIDE], data at [a+1][b+1].
// Written extents: ee r1..65 c1..65 | eo r1..65 c1..64
//                  oe r1..64 c1..65 | oo r1..64 c1..64
// ---------------------------------------------------------------------------
template <int PLANE>
__device__ __forceinline__ void passA_body(int bid, const bf16* __restrict__ xpad,
                                           const bf16* __restrict__ wt,
                                           _Float16* __restrict__ yy, int nimg,
                                           bf16* ldsW, bf16* ldsX) {
  constexpr int M = (PLANE == 0) ? 4225 : (PLANE == 3) ? 4096 : 4160;
  constexpr int T = (M + 255) >> 8;
  constexpr int NT = (PLANE == 0) ? 4 : (PLANE == 3) ? 1 : 2;
  constexpr int NSTEP = NT * 4;  // (icb outer, tap inner)
  constexpr int AOFF = (PLANE >= 2) ? 1 : 0;
  constexpr int BOFF = (PLANE & 1) ? 1 : 0;
  constexpr int DW = (PLANE == 0 || PLANE == 2) ? 65 : 64;
  constexpr int TAPI_all[4][4] = {{0, 2, 6, 8}, {1, 7, 0, 0}, {3, 5, 0, 0}, {4, 0, 0, 0}};
  constexpr int TDY_all[4][4] = {{0, 0, 1, 1}, {0, 1, 0, 0}, {0, 0, 0, 0}, {0, 0, 0, 0}};
  constexpr int TDX_all[4][4] = {{0, 1, 0, 1}, {0, 0, 0, 0}, {0, 1, 0, 0}, {0, 0, 0, 0}};
  constexpr int MAXS = TDY_all[PLANE][NT - 1] * DW + TDX_all[PLANE][NT - 1];
  constexpr int UR = 256 + MAXS;        // X union rows

  const int t = threadIdx.x;
  const int oct = bid & 1;
  const int tmp = bid >> 1;
  const int tile = tmp % T;
  const int nl = tmp / T;
  const int m0 = tile * 256;
  const int oc0 = oct * 128;
  const bf16* xn = xpad + (size_t)nl * (66 * 66 * 256);
  _Float16* yn = yy + ((size_t)(PLANE * nimg + nl) * 256) * YSTRIDE;

  const int w = t >> 6, lane = t & 63;
  const int wr = w & 1, wc = w >> 1;  // wr: oc 64-half, wc: m 64-quarter
  const int lr = lane & 15, lg = lane >> 4;

  auto dec = [](int m, int& a, int& b) {
    if (PLANE == 0 || PLANE == 2) { a = m / 65; b = m - a * 65; }
    else { a = m >> 6; b = m & 63; }
  };

  // W staging offsets: 1024 16B-chunks (2/thread), swizzled involution
  int wOffB[2];
#pragma unroll
  for (int r = 0; r < 2; ++r) {
    const int idx = r * 512 + t;
    const int row = idx >> 3;  // 0..127
    wOffB[r] = ((oc0 + row) * 256) * 2 + (((idx & 7) * 16) ^ ((row & 7) << 4));
  }

  // X union staging offsets: UR*8 chunks, <=6/thread. Rows >= M redirect to
  // xpad's all-zero ring row 65 (required: shifted taps READ those rows).
  int xOffU[6];
  const int nxc = (UR * 8 - t + 511) >> 9;  // chunks this thread owns
#pragma unroll
  for (int k = 0; k < 6; ++k) {
    const int cidx = k * 512 + t;
    if (cidx < UR * 8) {
      const int row = cidx >> 3;
      const int swz = ((cidx & 7) * 16) ^ ((row & 7) << 4);
      const int ms = m0 + row;
      if (ms < M) {
        int a, b;
        dec(ms, a, b);
        xOffU[k] = (((a + AOFF) * 66 + (b + BOFF)) * 256) * 2 + swz;
      } else {
        xOffU[k] = (65 * 66 * 256) * 2 + swz;  // zero row
      }
    }
  }

  auto stage_w = [&](int step) {
    const int tap = step % NT, icb = step / NT;
    const int wtoff = (TAPI_all[PLANE][tap] * 65536 + icb * 64) * 2;
#pragma unroll
    for (int r = 0; r < 2; ++r)
      __builtin_amdgcn_global_load_lds(AS1((const char*)wt + wOffB[r] + wtoff),
                                       AS3(ldsW + (size_t)(r * 512 + (t & 448)) * 8), 16, 0, 0);
  };

  auto stage_x = [&](int icb) {
    const int xtoffB = icb * 128;  // 64 ch * 2B
    for (int k = 0; k < nxc; ++k) {
      const int cidx = k * 512 + t;
      __builtin_amdgcn_global_load_lds(AS1((const char*)xn + xOffU[k] + xtoffB),
                                       AS3(ldsX + (size_t)(cidx & ~63) * 8), 16, 0, 0);
    }
  };

  f32x4 acc[4][4];
#pragma unroll
  for (int i = 0; i < 4; ++i)
#pragma unroll
    for (int j = 0; j < 4; ++j) acc[i][j] = (f32x4){0.f, 0.f, 0.f, 0.f};

  for (int step = 0; step < NSTEP; ++step) {
    const int icb = step / NT, tap = step - icb * NT;
    stage_w(step);
    if (tap == 0) stage_x(icb);
    __syncthreads();  // vmcnt(0) drain: W (+X) ready for all waves

    const int sOff = TDY_all[PLANE][tap] * DW + TDX_all[PLANE][tap];
#pragma unroll
    for (int kk = 0; kk < 2; ++kk) {
      bf16x8 af[4], bfr[4];
#pragma unroll
      for (int i = 0; i < 4; ++i) {
        const int row = wr * 64 + i * 16 + lr;
        const int off = row * 128 + ((kk * 64 + lg * 16) ^ ((row & 7) << 4));
        af[i] = *(const bf16x8*)((const char*)ldsW + off);
      }
#pragma unroll
      for (int j = 0; j < 4; ++j) {
        const int row = wc * 64 + j * 16 + lr + sOff;
        const int off = row * 128 + ((kk * 64 + lg * 16) ^ ((row & 7) << 4));
        bfr[j] = *(const bf16x8*)((const char*)ldsX + off);
      }
#pragma unroll
      for (int i = 0; i < 4; ++i)
#pragma unroll
        for (int j = 0; j < 4; ++j)
          acc[i][j] = __builtin_amdgcn_mfma_f32_16x16x32_bf16(af[i], bfr[j], acc[i][j], 0, 0, 0);
    }
    __syncthreads();  // all waves done reading before next overwrite
  }

  // epilogue: planar scalar stores, 16-lane groups -> contiguous 32B runs
#pragma unroll
  for (int i = 0; i < 4; ++i) {
    const int ocb = oc0 + wr * 64 + i * 16 + lg * 4;
#pragma unroll
    for (int j = 0; j < 4; ++j) {
      const int m = m0 + wc * 64 + j * 16 + lr;
      if (m < M) {
        int a, b;
        dec(m, a, b);
        const size_t sp = (size_t)(a + 1) * 66 + (b + 1);
#pragma unroll
        for (int reg = 0; reg < 4; ++reg)
          yn[(size_t)(ocb + reg) * YSTRIDE + sp] = (_Float16)acc[i][j][reg];
      }
    }
  }
}

__global__ __launch_bounds__(512) void passA_all(const bf16* __restrict__ xpad,
                                                 const bf16* __restrict__ wt,
                                                 _Float16* __restrict__ yy, int nimg) {
  __shared__ __attribute__((aligned(16))) bf16 ldsW[128 * 64];   // 16 KB
  __shared__ __attribute__((aligned(16))) bf16 ldsX[328 * 64];   // 42 KB
  int bid = blockIdx.x;
  const int S0 = nimg * 34, S1 = nimg * 34, S2 = nimg * 34;  // p3: nimg*32
  if (bid < S0) { passA_body<0>(xcdswz(bid, S0), xpad, wt, yy, nimg, ldsW, ldsX); return; }
  bid -= S0;
  if (bid < S1) { passA_body<1>(xcdswz(bid, S1), xpad, wt, yy, nimg, ldsW, ldsX); return; }
  bid -= S1;
  if (bid < S2) { passA_body<2>(xcdswz(bid, S2), xpad, wt, yy, nimg, ldsW, ldsX); return; }
  bid -= S2;
  passA_body<3>(xcdswz(bid, nimg * 32), xpad, wt, yy, nimg, ldsW, ldsX);
}

// ---------------------------------------------------------------------------
// Pass B v4 (unchanged, proven R13): LDS-staged depthwise FIR, column-
// vectorized. Block = (n,c,half); thread owns col-quad q x 4 row-pairs.
// ---------------------------------------------------------------------------
#define BSTRIDE 2248  // 34*66=2244 padded to 16B multiple

__global__ void passB_k(const _Float16* __restrict__ yy, const float* __restrict__ bias,
                        float* __restrict__ out, int nimg, int n0) {
  __shared__ _Float16 ldsY[4][BSTRIDE];
  const int b = blockIdx.x;
  const int h = b & 1, c = (b >> 1) & 255, nl = b >> 9;
  const int R0 = h * 32;
  const int t = threadIdx.x;
  const size_t PS = (size_t)nimg * 256 * YSTRIDE;
  const _Float16* base = yy + ((size_t)nl * 256 + c) * YSTRIDE;

  for (int idx = t; idx < 4 * 281; idx += 256) {
    const int pl = idx / 281, off = idx - pl * 281;
    *(float4*)(&ldsY[pl][off * 8]) =
        *(const float4*)((const char*)(base + (size_t)pl * PS) + R0 * 132 + (size_t)off * 16);
  }
  __syncthreads();
  const int brel = h ? 33 : 0;
  for (int idx = t; idx < 268; idx += 256) {
    if (idx < 68) {
      const int r = idx >> 1, col = (idx & 1) * 65;
      ldsY[1][r * 66 + col] = (_Float16)0.f;
    } else if (idx < 134) {
      ldsY[2][brel * 66 + (idx - 68)] = (_Float16)0.f;
    } else if (idx < 200) {
      ldsY[3][brel * 66 + (idx - 134)] = (_Float16)0.f;
    } else {
      const int k = idx - 200;
      const int r = k >> 1, col = (k & 1) * 65;
      ldsY[3][r * 66 + col] = (_Float16)0.f;
    }
  }
  __syncthreads();

  const int q = t & 31, g = t >> 5;
  const float bv = bias[c];
  float* ob = out + ((size_t)(n0 + nl) * 256 + c) * 16384;
  const int r0 = g * 4;

  float eeA[4], eeB[4], oeA[4], oeB[4], oeC[4];
  float eoA[4], eoB[4], ooA[4], ooB[4], ooC[4];

#define LD4(dst, pl, row)                                          \
  { const h2 u0 = *(const h2*)(&ldsY[pl][(row) * 66 + 2 * q]);     \
    const h2 u1 = *(const h2*)(&ldsY[pl][(row) * 66 + 2 * q + 2]); \
    dst[0] = (float)u0[0]; dst[1] = (float)u0[1];                  \
    dst[2] = (float)u1[0]; dst[3] = (float)u1[1]; }

  LD4(eeA, 0, r0 + 1); LD4(eeB, 0, r0 + 2);
  LD4(oeA, 2, r0);     LD4(oeB, 2, r0 + 1); LD4(oeC, 2, r0 + 2);
  LD4(eoA, 1, r0 + 1); LD4(eoB, 1, r0 + 2);
  LD4(ooA, 3, r0);     LD4(ooB, 3, r0 + 1); LD4(ooC, 3, r0 + 2);

#pragma unroll
  for (int oi = 0; oi < 4; ++oi) {
    const int o = R0 + r0 + oi;
    float rceq[2][3], rcoq[2][4];
#pragma unroll
    for (int k = 0; k < 3; ++k) {
      const int vi = k + 1;
      rceq[0][k] = 0.75f * eeA[vi] + 0.25f * eeB[vi] + 0.25f * oeA[vi] + 0.75f * oeB[vi];
      rceq[1][k] = 0.25f * eeA[vi] + 0.75f * eeB[vi] + 0.75f * oeB[vi] + 0.25f * oeC[vi];
    }
#pragma unroll
    for (int k = 0; k < 4; ++k) {
      rcoq[0][k] = 0.75f * eoA[k] + 0.25f * eoB[k] + 0.25f * ooA[k] + 0.75f * ooB[k];
      rcoq[1][k] = 0.25f * eoA[k] + 0.75f * eoB[k] + 0.75f * ooB[k] + 0.25f * ooC[k];
    }
#pragma unroll
    for (int py = 0; py < 2; ++py) {
      float4 st;
      st.x = 0.75f * rceq[py][0] + 0.25f * rceq[py][1] + 0.25f * rcoq[py][0] +
             0.75f * rcoq[py][1] + bv;
      st.y = 0.25f * rceq[py][0] + 0.75f * rceq[py][1] + 0.75f * rcoq[py][1] +
             0.25f * rcoq[py][2] + bv;
      st.z = 0.75f * rceq[py][1] + 0.25f * rceq[py][2] + 0.25f * rcoq[py][1] +
             0.75f * rcoq[py][2] + bv;
      st.w = 0.25f * rceq[py][1] + 0.75f * rceq[py][2] + 0.75f * rcoq[py][2] +
             0.25f * rcoq[py][3] + bv;
      *(float4*)(ob + ((size_t)(2 * o + py)) * 128 + 4 * q) = st;
    }
    if (oi < 3) {
#pragma unroll
      for (int k = 0; k < 4; ++k) {
        eeA[k] = eeB[k]; oeA[k] = oeB[k]; oeB[k] = oeC[k];
        eoA[k] = eoB[k]; ooA[k] = ooB[k]; ooB[k] = ooC[k];
      }
      LD4(eeB, 0, r0 + oi + 3);
      LD4(oeC, 2, r0 + oi + 3);
      LD4(eoB, 1, r0 + oi + 3);
      LD4(ooC, 3, r0 + oi + 3);
    }
  }
#undef LD4
}

// ---------------------------------------------------------------------------
extern "C" void kernel_launch(void* const* d_in, const int* in_sizes, int n_in,
                              void* d_out, int out_size, void* d_ws, size_t ws_size,
                              hipStream_t stream) {
  const float* x = (const float*)d_in[0];
  const float* wgt = (const float*)d_in[1];
  const float* bias = (const float*)d_in[2];
  float* out = (float*)d_out;

  const size_t XPL = (size_t)66 * 66 * 256;        // xpad elems per n
  const size_t YPN = (size_t)4 * 256 * YSTRIDE;    // y elems per n
  const size_t WT_BYTES = (size_t)9 * 256 * 256 * 2;
  int c = 0;
  const int cands[5] = {16, 8, 4, 2, 1};
  for (int ci = 0; ci < 5; ++ci)
    if (WT_BYTES + (size_t)cands[ci] * (XPL + YPN) * 2 <= ws_size) { c = cands[ci]; break; }
  if (c == 0) return;

  bf16* wt = (bf16*)d_ws;
  bf16* xpad = (bf16*)((char*)d_ws + WT_BYTES);
  _Float16* yy = (_Float16*)((char*)d_ws + WT_BYTES + (size_t)c * XPL * 2);

  prep_wt_k<<<256, 256, 0, stream>>>(wgt, wt);

  for (int k = 0; k < 16 / c; ++k) {
    zring_k<<<c * 33, 256, 0, stream>>>(xpad);
    xpose_k<<<c * 256, 256, 0, stream>>>(x + (size_t)k * c * 1048576, xpad);
    passA_all<<<c * 134, 512, 0, stream>>>(xpad, wt, yy, c);
    passB_k<<<c * 512, 256, 0, stream>>>(yy, bias, out, c, k * c);
  }
}

// Round 19
// 233.389 us; speedup vs baseline: 1.0508x; 1.0508x over previous
//
#include <hip/hip_runtime.h>
#include <hip/hip_bf16.h>

using bf16 = __hip_bfloat16;
typedef __bf16 bf16x8 __attribute__((ext_vector_type(8)));
typedef float f32x4 __attribute__((ext_vector_type(4)));
typedef short short8 __attribute__((ext_vector_type(8)));
typedef _Float16 h2 __attribute__((ext_vector_type(2)));

#define AS1(p) ((const __attribute__((address_space(1))) void*)(p))
#define AS3(p) ((__attribute__((address_space(3))) void*)(p))

#define YSTRIDE 4368  // 66*66 padded to 273*16B

// ---------------------------------------------------------------------------
// Weights: Wt[tap = p*3+q][oc][ic] bf16
// ---------------------------------------------------------------------------
__global__ void prep_wt_k(const float* __restrict__ w, bf16* __restrict__ wt) {
  const int o = blockIdx.x, i = threadIdx.x;
  const float* wp = w + (size_t)(o * 256 + i) * 9;
#pragma unroll
  for (int p = 0; p < 9; ++p)
    wt[(size_t)p * 65536 + o * 256 + i] = __float2bfloat16(wp[p]);
}

// ---------------------------------------------------------------------------
// Zero ONLY the xpad border ring (rows 0/65, cols 0/65) -- runs every call.
// Row 65 doubles as the all-zero redirect target for tap-union staging.
// ---------------------------------------------------------------------------
__global__ void zring_k(bf16* __restrict__ xpad) {
  const int bid = blockIdx.x;
  const int n = bid / 33, cg = bid - n * 33;
  const int t = threadIdx.x;
  const int cell = cg * 8 + (t >> 5);
  if (cell >= 260) return;
  int row, col;
  if (cell < 66) { row = 0; col = cell; }
  else if (cell < 132) { row = 65; col = cell - 66; }
  else if (cell < 196) { row = cell - 131; col = 0; }
  else { row = cell - 195; col = 65; }
  const int ch = (t & 31) * 8;
  short8 z = {0, 0, 0, 0, 0, 0, 0, 0};
  *(short8*)(xpad + (((size_t)n * 66 + row) * 66 + col) * 256 + ch) = z;
}

// ---------------------------------------------------------------------------
// x NCHW fp32 -> padded NHWC bf16 [n][66][66][256] (interior only).
// Coalesced reads: lane = (c = t>>2, ixq = t&3), 64B contiguous per lane.
// ---------------------------------------------------------------------------
__global__ void xpose_k(const float* __restrict__ x, bf16* __restrict__ xpad) {
  const int b = blockIdx.x;
  const int icb = b & 3, iy = (b >> 2) & 63, n = b >> 8;
  __shared__ bf16 lds[64][72];
  const int t = threadIdx.x;
  const int c = t >> 2, ixq = t & 3;
  const float* src = x + (((size_t)(n * 256 + icb * 64 + c) * 64 + iy) * 64);
#pragma unroll
  for (int rep = 0; rep < 4; ++rep) {
    const int ix0 = ixq * 16 + rep * 4;
    float4 v = *reinterpret_cast<const float4*>(src + ix0);
    lds[ix0 + 0][c] = __float2bfloat16(v.x);
    lds[ix0 + 1][c] = __float2bfloat16(v.y);
    lds[ix0 + 2][c] = __float2bfloat16(v.z);
    lds[ix0 + 3][c] = __float2bfloat16(v.w);
  }
  __syncthreads();
  const int ix = t >> 2, cseg = (t & 3) * 16;
  bf16* dst = xpad + (((size_t)(n * 66 + iy + 1) * 66 + ix + 1) * 256 + icb * 64 + cseg);
  *reinterpret_cast<short8*>(dst) = *reinterpret_cast<const short8*>(&lds[ix][cseg]);
  *reinterpret_cast<short8*>(dst + 8) = *reinterpret_cast<const short8*>(&lds[ix][cseg + 8]);
}

// ---------------------------------------------------------------------------
// Bijective XCD swizzle (m204)
// ---------------------------------------------------------------------------
__device__ __forceinline__ int xcdswz(int b, int n) {
  const int q = n >> 3, r = n & 7;
  const int xcd = b & 7, idx = b >> 3;
  return (xcd < r ? xcd * (q + 1) : r * (q + 1) + (xcd - r) * q) + idx;
}

// ---------------------------------------------------------------------------
// Pass A v5 (proven R16/R17): R13 loop + TAP-UNION X staging.
// 256oc x 256m per block, 512 thr (8 waves = 4 oc x 2 m, acc[4][8]),
// 2-phase double-buffer on W (per step) and X (per icb; union of all taps,
// shifted reads at row offsets S[tap]; b-wrap cells coincide with xpad's
// zero ring on both sides of the shift; rows past M redirect to zero row 65).
// y stored PLANAR fp16: y[plane][n][c][YSTRIDE], data at [a+1][b+1].
// Written extents: ee r1..65 c1..65 | eo r1..65 c1..64
//                  oe r1..64 c1..65 | oo r1..64 c1..64
// ---------------------------------------------------------------------------
template <int PLANE>
__device__ __forceinline__ void passA_body(int bid, const bf16* __restrict__ xpad,
                                           const bf16* __restrict__ wt,
                                           _Float16* __restrict__ yy, int nimg,
                                           bf16* ldsW, bf16* ldsX) {
  constexpr int M = (PLANE == 0) ? 4225 : (PLANE == 3) ? 4096 : 4160;
  constexpr int T = (M + 255) >> 8;
  constexpr int NT = (PLANE == 0) ? 4 : (PLANE == 3) ? 1 : 2;
  constexpr int NSTEP = NT * 4;  // (icb outer, tap inner)
  constexpr int AOFF = (PLANE >= 2) ? 1 : 0;
  constexpr int BOFF = (PLANE & 1) ? 1 : 0;
  constexpr int DW = (PLANE == 0 || PLANE == 2) ? 65 : 64;
  constexpr int TAPI_all[4][4] = {{0, 2, 6, 8}, {1, 7, 0, 0}, {3, 5, 0, 0}, {4, 0, 0, 0}};
  constexpr int TDY_all[4][4] = {{0, 0, 1, 1}, {0, 1, 0, 0}, {0, 0, 0, 0}, {0, 0, 0, 0}};
  constexpr int TDX_all[4][4] = {{0, 1, 0, 1}, {0, 0, 0, 0}, {0, 1, 0, 0}, {0, 0, 0, 0}};
  constexpr int MAXS = TDY_all[PLANE][NT - 1] * DW + TDX_all[PLANE][NT - 1];
  constexpr int UR = 256 + MAXS;        // X union rows
  constexpr int XBUF = 328 * 64;        // LDS X buffer elems (>= UR*64)

  const int t = threadIdx.x;
  const int tile = bid % T;
  const int nl = bid / T;
  const int m0 = tile * 256;
  const bf16* xn = xpad + (size_t)nl * (66 * 66 * 256);
  _Float16* yn = yy + ((size_t)(PLANE * nimg + nl) * 256) * YSTRIDE;

  const int w = t >> 6, lane = t & 63;
  const int wr = w >> 1, wc = w & 1;  // wr: oc quarter (0..3), wc: m half (0..1)
  const int lr = lane & 15, lg = lane >> 4;

  auto dec = [](int m, int& a, int& b) {
    if (PLANE == 0 || PLANE == 2) { a = m / 65; b = m - a * 65; }
    else { a = m >> 6; b = m & 63; }
  };

  // W staging offsets: 2048 16B-chunks (4/thread), swizzled involution
  int wOffB[4];
#pragma unroll
  for (int r = 0; r < 4; ++r) {
    const int idx = r * 512 + t;
    const int row = idx >> 3;
    wOffB[r] = (row * 256) * 2 + (((idx & 7) * 16) ^ ((row & 7) << 4));
  }

  // X union staging offsets: UR*8 chunks, <=6/thread. Rows >= M redirect to
  // xpad's all-zero ring row 65 (required: shifted taps READ those rows).
  int xOffU[6];
  const int nxc = (UR * 8 - t + 511) >> 9;  // chunks this thread owns
#pragma unroll
  for (int k = 0; k < 6; ++k) {
    const int cidx = k * 512 + t;
    if (cidx < UR * 8) {
      const int row = cidx >> 3;
      const int swz = ((cidx & 7) * 16) ^ ((row & 7) << 4);
      const int ms = m0 + row;
      if (ms < M) {
        int a, b;
        dec(ms, a, b);
        xOffU[k] = (((a + AOFF) * 66 + (b + BOFF)) * 256) * 2 + swz;
      } else {
        xOffU[k] = (65 * 66 * 256) * 2 + swz;  // zero row
      }
    }
  }

  auto stage_w = [&](int step, int buf) {
    const int tap = step % NT, icb = step / NT;
    const int wtoff = (TAPI_all[PLANE][tap] * 65536 + icb * 64) * 2;
    bf16* lw = ldsW + (size_t)buf * (256 * 64);
#pragma unroll
    for (int r = 0; r < 4; ++r)
      __builtin_amdgcn_global_load_lds(AS1((const char*)wt + wOffB[r] + wtoff),
                                       AS3(lw + (size_t)(r * 512 + (t & 448)) * 8), 16, 0, 0);
  };

  auto stage_x = [&](int icb, int buf) {
    const int xtoffB = icb * 128;  // 64 ch * 2B
    bf16* lx = ldsX + (size_t)buf * XBUF;
    for (int k = 0; k < nxc; ++k) {
      const int cidx = k * 512 + t;
      __builtin_amdgcn_global_load_lds(AS1((const char*)xn + xOffU[k] + xtoffB),
                                       AS3(lx + (size_t)(cidx & ~63) * 8), 16, 0, 0);
    }
  };

  f32x4 acc[4][8];
#pragma unroll
  for (int i = 0; i < 4; ++i)
#pragma unroll
    for (int j = 0; j < 8; ++j) acc[i][j] = (f32x4){0.f, 0.f, 0.f, 0.f};

  stage_w(0, 0);
  stage_x(0, 0);
  __syncthreads();  // step-0 buffers ready

  for (int step = 0; step < NSTEP; ++step) {
    const int icb = step / NT, tap = step - icb * NT;
    const int next = step + 1;
    if (next < NSTEP) {
      stage_w(next, next & 1);
      if (next - (next / NT) * NT == 0) stage_x(next / NT, (next / NT) & 1);
    }
    const int sOff = TDY_all[PLANE][tap] * DW + TDX_all[PLANE][tap];
    const bf16* lw = ldsW + (size_t)(step & 1) * (256 * 64);
    const bf16* lx = ldsX + (size_t)(icb & 1) * XBUF;
#pragma unroll
    for (int kk = 0; kk < 2; ++kk) {
      bf16x8 af[4], bfr[8];
#pragma unroll
      for (int i = 0; i < 4; ++i) {
        const int row = wr * 64 + i * 16 + lr;
        const int off = row * 128 + ((kk * 64 + lg * 16) ^ ((row & 7) << 4));
        af[i] = *(const bf16x8*)((const char*)lw + off);
      }
#pragma unroll
      for (int j = 0; j < 8; ++j) {
        const int row = wc * 128 + j * 16 + lr + sOff;
        const int off = row * 128 + ((kk * 64 + lg * 16) ^ ((row & 7) << 4));
        bfr[j] = *(const bf16x8*)((const char*)lx + off);
      }
#pragma unroll
      for (int i = 0; i < 4; ++i)
#pragma unroll
        for (int j = 0; j < 8; ++j)
          acc[i][j] = __builtin_amdgcn_mfma_f32_16x16x32_bf16(af[i], bfr[j], acc[i][j], 0, 0, 0);
    }
    __syncthreads();  // drains prefetch + protects buffer reuse (R13 pattern)
  }

  // epilogue: planar scalar stores, 16-lane groups -> contiguous 32B runs
#pragma unroll
  for (int i = 0; i < 4; ++i) {
    const int ocb = wr * 64 + i * 16 + lg * 4;
#pragma unroll
    for (int j = 0; j < 8; ++j) {
      const int m = m0 + wc * 128 + j * 16 + lr;
      if (m < M) {
        int a, b;
        dec(m, a, b);
        const size_t sp = (size_t)(a + 1) * 66 + (b + 1);
#pragma unroll
        for (int reg = 0; reg < 4; ++reg)
          yn[(size_t)(ocb + reg) * YSTRIDE + sp] = (_Float16)acc[i][j][reg];
      }
    }
  }
}

__global__ __launch_bounds__(512) void passA_all(const bf16* __restrict__ xpad,
                                                 const bf16* __restrict__ wt,
                                                 _Float16* __restrict__ yy, int nimg) {
  __shared__ __attribute__((aligned(16))) bf16 ldsW[2][256 * 64];   //  64 KB
  __shared__ __attribute__((aligned(16))) bf16 ldsX[2][328 * 64];   //  82 KB
  int bid = blockIdx.x;
  const int S0 = nimg * 17, S1 = nimg * 17, S2 = nimg * 17;
  if (bid < S0) { passA_body<0>(xcdswz(bid, S0), xpad, wt, yy, nimg, &ldsW[0][0], &ldsX[0][0]); return; }
  bid -= S0;
  if (bid < S1) { passA_body<1>(xcdswz(bid, S1), xpad, wt, yy, nimg, &ldsW[0][0], &ldsX[0][0]); return; }
  bid -= S1;
  if (bid < S2) { passA_body<2>(xcdswz(bid, S2), xpad, wt, yy, nimg, &ldsW[0][0], &ldsX[0][0]); return; }
  bid -= S2;
  passA_body<3>(xcdswz(bid, nimg * 16), xpad, wt, yy, nimg, &ldsW[0][0], &ldsX[0][0]);
}

// ---------------------------------------------------------------------------
// Pass B v4 (proven R13): LDS-staged depthwise FIR, column-vectorized.
// Block = (n,c,half); thread owns col-quad q x 4 row-pairs.
// ---------------------------------------------------------------------------
#define BSTRIDE 2248  // 34*66=2244 padded to 16B multiple

__global__ void passB_k(const _Float16* __restrict__ yy, const float* __restrict__ bias,
                        float* __restrict__ out, int nimg, int n0) {
  __shared__ _Float16 ldsY[4][BSTRIDE];
  const int b = blockIdx.x;
  const int h = b & 1, c = (b >> 1) & 255, nl = b >> 9;
  const int R0 = h * 32;
  const int t = threadIdx.x;
  const size_t PS = (size_t)nimg * 256 * YSTRIDE;
  const _Float16* base = yy + ((size_t)nl * 256 + c) * YSTRIDE;

  for (int idx = t; idx < 4 * 281; idx += 256) {
    const int pl = idx / 281, off = idx - pl * 281;
    *(float4*)(&ldsY[pl][off * 8]) =
        *(const float4*)((const char*)(base + (size_t)pl * PS) + R0 * 132 + (size_t)off * 16);
  }
  __syncthreads();
  const int brel = h ? 33 : 0;
  for (int idx = t; idx < 268; idx += 256) {
    if (idx < 68) {
      const int r = idx >> 1, col = (idx & 1) * 65;
      ldsY[1][r * 66 + col] = (_Float16)0.f;
    } else if (idx < 134) {
      ldsY[2][brel * 66 + (idx - 68)] = (_Float16)0.f;
    } else if (idx < 200) {
      ldsY[3][brel * 66 + (idx - 134)] = (_Float16)0.f;
    } else {
      const int k = idx - 200;
      const int r = k >> 1, col = (k & 1) * 65;
      ldsY[3][r * 66 + col] = (_Float16)0.f;
    }
  }
  __syncthreads();

  const int q = t & 31, g = t >> 5;
  const float bv = bias[c];
  float* ob = out + ((size_t)(n0 + nl) * 256 + c) * 16384;
  const int r0 = g * 4;

  float eeA[4], eeB[4], oeA[4], oeB[4], oeC[4];
  float eoA[4], eoB[4], ooA[4], ooB[4], ooC[4];

#define LD4(dst, pl, row)                                          \
  { const h2 u0 = *(const h2*)(&ldsY[pl][(row) * 66 + 2 * q]);     \
    const h2 u1 = *(const h2*)(&ldsY[pl][(row) * 66 + 2 * q + 2]); \
    dst[0] = (float)u0[0]; dst[1] = (float)u0[1];                  \
    dst[2] = (float)u1[0]; dst[3] = (float)u1[1]; }

  LD4(eeA, 0, r0 + 1); LD4(eeB, 0, r0 + 2);
  LD4(oeA, 2, r0);     LD4(oeB, 2, r0 + 1); LD4(oeC, 2, r0 + 2);
  LD4(eoA, 1, r0 + 1); LD4(eoB, 1, r0 + 2);
  LD4(ooA, 3, r0);     LD4(ooB, 3, r0 + 1); LD4(ooC, 3, r0 + 2);

#pragma unroll
  for (int oi = 0; oi < 4; ++oi) {
    const int o = R0 + r0 + oi;
    float rceq[2][3], rcoq[2][4];
#pragma unroll
    for (int k = 0; k < 3; ++k) {
      const int vi = k + 1;
      rceq[0][k] = 0.75f * eeA[vi] + 0.25f * eeB[vi] + 0.25f * oeA[vi] + 0.75f * oeB[vi];
      rceq[1][k] = 0.25f * eeA[vi] + 0.75f * eeB[vi] + 0.75f * oeB[vi] + 0.25f * oeC[vi];
    }
#pragma unroll
    for (int k = 0; k < 4; ++k) {
      rcoq[0][k] = 0.75f * eoA[k] + 0.25f * eoB[k] + 0.25f * ooA[k] + 0.75f * ooB[k];
      rcoq[1][k] = 0.25f * eoA[k] + 0.75f * eoB[k] + 0.75f * ooB[k] + 0.25f * ooC[k];
    }
#pragma unroll
    for (int py = 0; py < 2; ++py) {
      float4 st;
      st.x = 0.75f * rceq[py][0] + 0.25f * rceq[py][1] + 0.25f * rcoq[py][0] +
             0.75f * rcoq[py][1] + bv;
      st.y = 0.25f * rceq[py][0] + 0.75f * rceq[py][1] + 0.75f * rcoq[py][1] +
             0.25f * rcoq[py][2] + bv;
      st.z = 0.75f * rceq[py][1] + 0.25f * rceq[py][2] + 0.25f * rcoq[py][1] +
             0.75f * rcoq[py][2] + bv;
      st.w = 0.25f * rceq[py][1] + 0.75f * rceq[py][2] + 0.75f * rcoq[py][2] +
             0.25f * rcoq[py][3] + bv;
      *(float4*)(ob + ((size_t)(2 * o + py)) * 128 + 4 * q) = st;
    }
    if (oi < 3) {
#pragma unroll
      for (int k = 0; k < 4; ++k) {
        eeA[k] = eeB[k]; oeA[k] = oeB[k]; oeB[k] = oeC[k];
        eoA[k] = eoB[k]; ooA[k] = ooB[k]; ooB[k] = ooC[k];
      }
      LD4(eeB, 0, r0 + oi + 3);
      LD4(oeC, 2, r0 + oi + 3);
      LD4(eoB, 1, r0 + oi + 3);
      LD4(ooC, 3, r0 + oi + 3);
    }
  }
#undef LD4
}

// ---------------------------------------------------------------------------
extern "C" void kernel_launch(void* const* d_in, const int* in_sizes, int n_in,
                              void* d_out, int out_size, void* d_ws, size_t ws_size,
                              hipStream_t stream) {
  const float* x = (const float*)d_in[0];
  const float* wgt = (const float*)d_in[1];
  const float* bias = (const float*)d_in[2];
  float* out = (float*)d_out;

  const size_t XPL = (size_t)66 * 66 * 256;        // xpad elems per n
  const size_t YPN = (size_t)4 * 256 * YSTRIDE;    // y elems per n
  const size_t WT_BYTES = (size_t)9 * 256 * 256 * 2;
  int c = 0;
  const int cands[5] = {16, 8, 4, 2, 1};
  for (int ci = 0; ci < 5; ++ci)
    if (WT_BYTES + (size_t)cands[ci] * (XPL + YPN) * 2 <= ws_size) { c = cands[ci]; break; }
  if (c == 0) return;

  bf16* wt = (bf16*)d_ws;
  bf16* xpad = (bf16*)((char*)d_ws + WT_BYTES);
  _Float16* yy = (_Float16*)((char*)d_ws + WT_BYTES + (size_t)c * XPL * 2);

  prep_wt_k<<<256, 256, 0, stream>>>(wgt, wt);

  for (int k = 0; k < 16 / c; ++k) {
    zring_k<<<c * 33, 256, 0, stream>>>(xpad);
    xpose_k<<<c * 256, 256, 0, stream>>>(x + (size_t)k * c * 1048576, xpad);
    passA_all<<<c * 67, 512, 0, stream>>>(xpad, wt, yy, c);
    passB_k<<<c * 512, 256, 0, stream>>>(yy, bias, out, c, k * c);
  }
}